// Round 1
// baseline (14413.885 us; speedup 1.0000x reference)
//
#include <hip/hip_runtime.h>
#include <hip/hip_bf16.h>

#define H_DIM 4096
#define M_TOK 4096
#define V_DIM 32000
#define BM 128
#define BN 128
#define BK 64

typedef unsigned short ushort_t;
typedef __attribute__((ext_vector_type(8))) short short8;
typedef __attribute__((ext_vector_type(4))) float f32x4;

__device__ __forceinline__ unsigned short f2bf(float f) {
    unsigned int u = __float_as_uint(f);
    u += 0x7FFFu + ((u >> 16) & 1u);   // round-to-nearest-even
    return (unsigned short)(u >> 16);
}

// async global -> LDS, 16B per lane (wave-uniform base + lane*16 layout)
__device__ __forceinline__ void gl2lds16(const void* g, void* l) {
    __builtin_amdgcn_global_load_lds(
        (const __attribute__((address_space(1))) unsigned int*)g,
        (__attribute__((address_space(3))) unsigned int*)l, 16, 0, 0);
}

// ---------------- fp32 -> bf16 cast ----------------
__global__ void cast_f32_bf16(const float* __restrict__ src,
                              ushort_t* __restrict__ dst, size_t n) {
    size_t i = ((size_t)blockIdx.x * 256 + threadIdx.x) * 8;
    if (i >= n) return;
    float4 a = *(const float4*)(src + i);
    float4 b = *(const float4*)(src + i + 4);
    short8 p = { (short)f2bf(a.x), (short)f2bf(a.y), (short)f2bf(a.z), (short)f2bf(a.w),
                 (short)f2bf(b.x), (short)f2bf(b.y), (short)f2bf(b.z), (short)f2bf(b.w) };
    *(short8*)(dst + i) = p;
}

// ---------------- fused GEMM + exp-sum + label gather ----------------
// grid = 8 (xcd) * 32 (n_outer) * 32 (m tiles) = 8192 blocks, 256 threads.
// xcd swizzle: vocab tiles partitioned across XCDs so each W tile is read
// from HBM by one XCD only and served from its L2 across all 32 m-tiles.
template <bool WPRE>
__global__ __launch_bounds__(256) void gemm_fused(
    const ushort_t* __restrict__ xb,   // bf16 x  [4096 x 4096]
    const ushort_t* __restrict__ wb,   // bf16 W  [32000 x 4096] (WPRE)
    const float*    __restrict__ wf,   // fp32 W  (!WPRE)
    const int*      __restrict__ y,    // [4096]
    float* __restrict__ sums,          // [4096] sum of exp(logit)
    float* __restrict__ label)         // [4096] label logit
{
    int i = blockIdx.x;
    int xcd = i & 7;
    int j = i >> 3;
    int nouter = j >> 5;               // 0..31
    int mt = j & 31;                   // 0..31  (sweeps fastest per XCD)
    int ntile = xcd + 8 * nouter;      // 0..255
    if (ntile >= 250) return;          // 32000/128 = 250 vocab tiles
    int m0 = mt * BM;
    int n0 = ntile * BN;

    __shared__ ushort_t lA[BM * BK];   // 16 KB
    __shared__ ushort_t lB[BN * BK];   // 16 KB

    int t = threadIdx.x;
    int lane = t & 63;
    int wid = t >> 6;
    int wm = (wid >> 1) * 64;
    int wn = (wid & 1) * 64;
    int lrow = lane & 15;
    int lko = (lane >> 4) * 8;

    f32x4 acc[4][4] = {};

    // staging bases (thread t: row t/8, col (t%8)*8; rounds advance 32 rows)
    const ushort_t* ag = xb + (size_t)(m0 + (t >> 3)) * H_DIM + (t & 7) * 8;
    ushort_t* al = &lA[t * 8];
    const ushort_t* bg = WPRE ? (wb + (size_t)(n0 + (t >> 3)) * H_DIM + (t & 7) * 8) : (const ushort_t*)0;
    ushort_t* bl = &lB[t * 8];
    const float* wg = WPRE ? (const float*)0 : (wf + (size_t)(n0 + (t >> 1)) * H_DIM + (t & 1) * 32);
    ushort_t* wl = &lB[(t >> 1) * 64 + (t & 1) * 32];

    for (int kt = 0; kt < H_DIM; kt += BK) {
        #pragma unroll
        for (int r = 0; r < 4; r++)
            gl2lds16(ag + kt + (size_t)r * 32 * H_DIM, al + r * 2048);
        if (WPRE) {
            #pragma unroll
            for (int r = 0; r < 4; r++)
                gl2lds16(bg + kt + (size_t)r * 32 * H_DIM, bl + r * 2048);
        } else {
            #pragma unroll
            for (int q = 0; q < 4; q++) {
                float4 v0 = *(const float4*)(wg + kt + 8 * q);
                float4 v1 = *(const float4*)(wg + kt + 8 * q + 4);
                short8 p = { (short)f2bf(v0.x), (short)f2bf(v0.y), (short)f2bf(v0.z), (short)f2bf(v0.w),
                             (short)f2bf(v1.x), (short)f2bf(v1.y), (short)f2bf(v1.z), (short)f2bf(v1.w) };
                *(short8*)(wl + 8 * q) = p;
            }
        }
        __syncthreads();
        #pragma unroll
        for (int kk = 0; kk < BK; kk += 32) {
            short8 af[4], bfr[4];
            #pragma unroll
            for (int mi = 0; mi < 4; mi++)
                af[mi] = *(const short8*)&lA[(wm + mi * 16 + lrow) * BK + kk + lko];
            #pragma unroll
            for (int ni = 0; ni < 4; ni++)
                bfr[ni] = *(const short8*)&lB[(wn + ni * 16 + lrow) * BK + kk + lko];
            #pragma unroll
            for (int mi = 0; mi < 4; mi++)
                #pragma unroll
                for (int ni = 0; ni < 4; ni++)
                    acc[mi][ni] = __builtin_amdgcn_mfma_f32_16x16x32_bf16(
                        af[mi], bfr[ni], acc[mi][ni], 0, 0, 0);
        }
        __syncthreads();
    }

    // epilogue: label gather + exp row-sum -> atomicAdd
    int quad = lane >> 4;
    #pragma unroll
    for (int mi = 0; mi < 4; mi++) {
        #pragma unroll
        for (int ii = 0; ii < 4; ii++) {
            int row = wm + mi * 16 + quad * 4 + ii;   // C/D: row=(lane>>4)*4+reg
            int gm = m0 + row;
            int yv = y[gm];
            int c = yv - n0 - wn;                     // C/D: col=lane&15
            if (c >= 0 && c < 64 && (c & 15) == lrow)
                label[gm] = acc[mi][c >> 4][ii];
            float s = __expf(acc[mi][0][ii]) + __expf(acc[mi][1][ii]) +
                      __expf(acc[mi][2][ii]) + __expf(acc[mi][3][ii]);
            s += __shfl_xor(s, 1);
            s += __shfl_xor(s, 2);
            s += __shfl_xor(s, 4);
            s += __shfl_xor(s, 8);
            if (lrow == 0) atomicAdd(&sums[gm], s);
        }
    }
}

// ---------------- finalize: per-seq avg + CPO loss ----------------
__global__ void finalize_loss(const float* __restrict__ sums,
                              const float* __restrict__ label,
                              const int* __restrict__ y,
                              float* __restrict__ out) {
    __shared__ float red[512];
    __shared__ float redc[512];
    __shared__ float s_lp[8], s_cnt[8];
    int t = threadIdx.x;
    for (int s = 0; s < 8; s++) {
        int idx = s * 512 + t;
        int yv = y[idx];
        float maskf = (yv != -100) ? 1.0f : 0.0f;
        float lp = (label[idx] - logf(sums[idx])) * maskf;
        red[t] = lp;
        redc[t] = maskf;
        __syncthreads();
        for (int off = 256; off > 0; off >>= 1) {
            if (t < off) { red[t] += red[t + off]; redc[t] += redc[t + off]; }
            __syncthreads();
        }
        if (t == 0) { s_lp[s] = red[0]; s_cnt[s] = redc[0]; }
        __syncthreads();
    }
    if (t == 0) {
        float pref = 0.0f, nll_num = 0.0f, nll_den = 0.0f;
        for (int b = 0; b < 4; b++) {
            float avgc = s_lp[b] / s_cnt[b];
            float avgr = s_lp[b + 4] / s_cnt[b + 4];
            float d = 0.1f * (avgc - avgr);
            // log_sigmoid(d), numerically stable
            float ls = fminf(d, 0.0f) - log1pf(expf(-fabsf(d)));
            pref += -ls;                       // LABEL_SMOOTHING = 0
            nll_num += s_lp[b];
            nll_den += s_cnt[b];
        }
        pref *= 0.25f;                         // / B (=4)
        float nll = -nll_num / nll_den;
        out[0] = nll + pref;                   // ALPHA = 1
    }
}

extern "C" void kernel_launch(void* const* d_in, const int* in_sizes, int n_in,
                              void* d_out, int out_size, void* d_ws, size_t ws_size,
                              hipStream_t stream) {
    const float* x = (const float*)d_in[0];   // [8,512,4096] fp32
    const int*   y = (const int*)d_in[1];     // [8,512] int32
    const float* W = (const float*)d_in[2];   // [32000,4096] fp32
    float* out = (float*)d_out;

    char* ws = (char*)d_ws;
    ushort_t* xb   = (ushort_t*)ws;                         // 33,554,432 B
    float* sums    = (float*)(ws + 33554432);               // 16,384 B
    float* label   = (float*)(ws + 33554432 + 16384);       // 16,384 B
    ushort_t* Wb   = (ushort_t*)(ws + 33587200);            // 262,144,000 B
    bool wpre = ws_size >= 295731200ull;

    hipMemsetAsync(sums, 0, 32768, stream);  // zero sums + label

    cast_f32_bf16<<<8192, 256, 0, stream>>>(x, xb, (size_t)16777216);
    if (wpre) {
        cast_f32_bf16<<<64000, 256, 0, stream>>>(W, Wb, (size_t)131072000);
        gemm_fused<true><<<8192, 256, 0, stream>>>(xb, Wb, (const float*)0, y, sums, label);
    } else {
        gemm_fused<false><<<8192, 256, 0, stream>>>(xb, (const ushort_t*)0, W, y, sums, label);
    }
    finalize_loss<<<1, 512, 0, stream>>>(sums, label, y, out);
}

// Round 2
// 2407.377 us; speedup vs baseline: 5.9874x; 5.9874x over previous
//
#include <hip/hip_runtime.h>
#include <hip/hip_bf16.h>

#define H_DIM 4096
#define M_TOK 4096
#define V_DIM 32000
#define BM 128
#define BN 128
#define BK 64

typedef unsigned short ushort_t;
typedef __attribute__((ext_vector_type(8))) short short8;
typedef __attribute__((ext_vector_type(4))) float f32x4;

__device__ __forceinline__ unsigned short f2bf(float f) {
    unsigned int u = __float_as_uint(f);
    u += 0x7FFFu + ((u >> 16) & 1u);   // round-to-nearest-even
    return (unsigned short)(u >> 16);
}

// async global -> LDS, 16B per lane (wave-uniform base + lane*16 layout)
__device__ __forceinline__ void gl2lds16(const void* g, void* l) {
    __builtin_amdgcn_global_load_lds(
        (const __attribute__((address_space(1))) unsigned int*)g,
        (__attribute__((address_space(3))) unsigned int*)l, 16, 0, 0);
}

// ---------------- fp32 -> bf16 cast ----------------
__global__ void cast_f32_bf16(const float* __restrict__ src,
                              ushort_t* __restrict__ dst, size_t n) {
    size_t i = ((size_t)blockIdx.x * 256 + threadIdx.x) * 8;
    if (i >= n) return;
    float4 a = *(const float4*)(src + i);
    float4 b = *(const float4*)(src + i + 4);
    short8 p = { (short)f2bf(a.x), (short)f2bf(a.y), (short)f2bf(a.z), (short)f2bf(a.w),
                 (short)f2bf(b.x), (short)f2bf(b.y), (short)f2bf(b.z), (short)f2bf(b.w) };
    *(short8*)(dst + i) = p;
}

// ---------------- fused GEMM + exp-sum + label gather ----------------
// grid = 8 (xcd) * 32 (n_outer) * 32 (m tiles) = 8192 blocks, 256 threads.
// xcd swizzle: vocab tiles partitioned across XCDs so each W tile is read
// from HBM by one XCD only and served from its L2 across all 32 m-tiles.
template <bool WPRE>
__global__ __launch_bounds__(256) void gemm_fused(
    const ushort_t* __restrict__ xb,   // bf16 x  [4096 x 4096]
    const ushort_t* __restrict__ wb,   // bf16 W  [32000 x 4096] (WPRE)
    const float*    __restrict__ wf,   // fp32 W  (!WPRE)
    const int*      __restrict__ y,    // [4096]
    float* __restrict__ sums,          // [4096] sum of exp(logit)
    float* __restrict__ label)         // [4096] label logit
{
    int i = blockIdx.x;
    int xcd = i & 7;
    int j = i >> 3;
    int nouter = j >> 5;               // 0..31
    int mt = j & 31;                   // 0..31  (sweeps fastest per XCD)
    int ntile = xcd + 8 * nouter;      // 0..255
    if (ntile >= 250) return;          // 32000/128 = 250 vocab tiles
    int m0 = mt * BM;
    int n0 = ntile * BN;

    __shared__ ushort_t lA[BM * BK];   // 16 KB
    __shared__ ushort_t lB[BN * BK];   // 16 KB

    int t = threadIdx.x;
    int lane = t & 63;
    int wid = t >> 6;
    int wm = (wid >> 1) * 64;
    int wn = (wid & 1) * 64;
    int lrow = lane & 15;
    int lko = (lane >> 4) * 8;

    f32x4 acc[4][4] = {};

    // staging bases (thread t: row t/8, col (t%8)*8; rounds advance 32 rows)
    const ushort_t* ag = xb + (size_t)(m0 + (t >> 3)) * H_DIM + (t & 7) * 8;
    ushort_t* al = &lA[t * 8];
    const ushort_t* bg = WPRE ? (wb + (size_t)(n0 + (t >> 3)) * H_DIM + (t & 7) * 8) : (const ushort_t*)0;
    ushort_t* bl = &lB[t * 8];
    const float* wg = WPRE ? (const float*)0 : (wf + (size_t)(n0 + (t >> 1)) * H_DIM + (t & 1) * 32);
    ushort_t* wl = &lB[(t >> 1) * 64 + (t & 1) * 32];

    for (int kt = 0; kt < H_DIM; kt += BK) {
        #pragma unroll
        for (int r = 0; r < 4; r++)
            gl2lds16(ag + kt + (size_t)r * 32 * H_DIM, al + r * 2048);
        if (WPRE) {
            #pragma unroll
            for (int r = 0; r < 4; r++)
                gl2lds16(bg + kt + (size_t)r * 32 * H_DIM, bl + r * 2048);
        } else {
            #pragma unroll
            for (int q = 0; q < 4; q++) {
                float4 v0 = *(const float4*)(wg + kt + 8 * q);
                float4 v1 = *(const float4*)(wg + kt + 8 * q + 4);
                short8 p = { (short)f2bf(v0.x), (short)f2bf(v0.y), (short)f2bf(v0.z), (short)f2bf(v0.w),
                             (short)f2bf(v1.x), (short)f2bf(v1.y), (short)f2bf(v1.z), (short)f2bf(v1.w) };
                *(short8*)(wl + 8 * q) = p;
            }
        }
        __syncthreads();
        #pragma unroll
        for (int kk = 0; kk < BK; kk += 32) {
            short8 af[4], bfr[4];
            #pragma unroll
            for (int mi = 0; mi < 4; mi++)
                af[mi] = *(const short8*)&lA[(wm + mi * 16 + lrow) * BK + kk + lko];
            #pragma unroll
            for (int ni = 0; ni < 4; ni++)
                bfr[ni] = *(const short8*)&lB[(wn + ni * 16 + lrow) * BK + kk + lko];
            #pragma unroll
            for (int mi = 0; mi < 4; mi++)
                #pragma unroll
                for (int ni = 0; ni < 4; ni++)
                    acc[mi][ni] = __builtin_amdgcn_mfma_f32_16x16x32_bf16(
                        af[mi], bfr[ni], acc[mi][ni], 0, 0, 0);
        }
        __syncthreads();
    }

    // epilogue: label gather + exp row-sum -> atomicAdd
    // NOTE: all acc[] indices must be compile-time constants — a dynamic
    // index demotes the accumulator to scratch (49 GB of HBM writes in R1).
    int quad = lane >> 4;
    #pragma unroll
    for (int mi = 0; mi < 4; mi++) {
        #pragma unroll
        for (int ii = 0; ii < 4; ii++) {
            int row = wm + mi * 16 + quad * 4 + ii;   // C/D: row=(lane>>4)*4+reg
            int gm = m0 + row;
            int yv = y[gm];
            int c = yv - n0 - wn;                     // C/D: col=lane&15
            #pragma unroll
            for (int ni = 0; ni < 4; ni++) {
                if (c == ni * 16 + lrow) label[gm] = acc[mi][ni][ii];
            }
            float s = __expf(acc[mi][0][ii]) + __expf(acc[mi][1][ii]) +
                      __expf(acc[mi][2][ii]) + __expf(acc[mi][3][ii]);
            s += __shfl_xor(s, 1);
            s += __shfl_xor(s, 2);
            s += __shfl_xor(s, 4);
            s += __shfl_xor(s, 8);
            if (lrow == 0) atomicAdd(&sums[gm], s);
        }
    }
}

// ---------------- finalize: per-seq avg + CPO loss ----------------
__global__ void finalize_loss(const float* __restrict__ sums,
                              const float* __restrict__ label,
                              const int* __restrict__ y,
                              float* __restrict__ out) {
    __shared__ float red[512];
    __shared__ float redc[512];
    __shared__ float s_lp[8], s_cnt[8];
    int t = threadIdx.x;
    for (int s = 0; s < 8; s++) {
        int idx = s * 512 + t;
        int yv = y[idx];
        float maskf = (yv != -100) ? 1.0f : 0.0f;
        float lp = (label[idx] - logf(sums[idx])) * maskf;
        red[t] = lp;
        redc[t] = maskf;
        __syncthreads();
        for (int off = 256; off > 0; off >>= 1) {
            if (t < off) { red[t] += red[t + off]; redc[t] += redc[t + off]; }
            __syncthreads();
        }
        if (t == 0) { s_lp[s] = red[0]; s_cnt[s] = redc[0]; }
        __syncthreads();
    }
    if (t == 0) {
        float pref = 0.0f, nll_num = 0.0f, nll_den = 0.0f;
        for (int b = 0; b < 4; b++) {
            float avgc = s_lp[b] / s_cnt[b];
            float avgr = s_lp[b + 4] / s_cnt[b + 4];
            float d = 0.1f * (avgc - avgr);
            // log_sigmoid(d), numerically stable
            float ls = fminf(d, 0.0f) - log1pf(expf(-fabsf(d)));
            pref += -ls;                       // LABEL_SMOOTHING = 0
            nll_num += s_lp[b];
            nll_den += s_cnt[b];
        }
        pref *= 0.25f;                         // / B (=4)
        float nll = -nll_num / nll_den;
        out[0] = nll + pref;                   // ALPHA = 1
    }
}

extern "C" void kernel_launch(void* const* d_in, const int* in_sizes, int n_in,
                              void* d_out, int out_size, void* d_ws, size_t ws_size,
                              hipStream_t stream) {
    const float* x = (const float*)d_in[0];   // [8,512,4096] fp32
    const int*   y = (const int*)d_in[1];     // [8,512] int32
    const float* W = (const float*)d_in[2];   // [32000,4096] fp32
    float* out = (float*)d_out;

    char* ws = (char*)d_ws;
    ushort_t* xb   = (ushort_t*)ws;                         // 33,554,432 B
    float* sums    = (float*)(ws + 33554432);               // 16,384 B
    float* label   = (float*)(ws + 33554432 + 16384);       // 16,384 B
    ushort_t* Wb   = (ushort_t*)(ws + 33587200);            // 262,144,000 B
    bool wpre = ws_size >= 295731200ull;

    hipMemsetAsync(sums, 0, 32768, stream);  // zero sums + label

    cast_f32_bf16<<<8192, 256, 0, stream>>>(x, xb, (size_t)16777216);
    if (wpre) {
        cast_f32_bf16<<<64000, 256, 0, stream>>>(W, Wb, (size_t)131072000);
        gemm_fused<true><<<8192, 256, 0, stream>>>(xb, Wb, (const float*)0, y, sums, label);
    } else {
        gemm_fused<false><<<8192, 256, 0, stream>>>(xb, (const ushort_t*)0, W, y, sums, label);
    }
    finalize_loss<<<1, 512, 0, stream>>>(sums, label, y, out);
}